// Round 2
// baseline (664.571 us; speedup 1.0000x reference)
//
#include <hip/hip_runtime.h>
#include <hip/hip_bf16.h>

#define S_LEN 2048
#define HID   4096
#define NH    32
#define NKV   8
#define HD    128

typedef __attribute__((ext_vector_type(8))) short short8v;
typedef __attribute__((ext_vector_type(4))) float floatx4;

__device__ __forceinline__ float bf2f(unsigned short u) {
  union { unsigned int u32; float f; } v; v.u32 = ((unsigned int)u) << 16; return v.f;
}
__device__ __forceinline__ unsigned short f2bf(float f) {
  union { float f; unsigned int u; } v; v.f = f;
  unsigned int u = v.u + 0x7fffu + ((v.u >> 16) & 1u);
  return (unsigned short)(u >> 16);
}

__device__ __forceinline__ void gld_lds16(const void* g, void* l) {
  __builtin_amdgcn_global_load_lds((const __attribute__((address_space(1))) void*)g,
                                   (__attribute__((address_space(3))) void*)l, 16, 0, 0);
}

// ---------------- fused f32 -> bf16 convert for all 5 tensors ----------------
__global__ __launch_bounds__(256) void cvt_all(const float* __restrict__ X,  const float* __restrict__ Wq,
                                               const float* __restrict__ Wk, const float* __restrict__ Wv,
                                               const float* __restrict__ Wo,
                                               unsigned short* __restrict__ Xb,  unsigned short* __restrict__ Wqb,
                                               unsigned short* __restrict__ Wkb, unsigned short* __restrict__ Wvb,
                                               unsigned short* __restrict__ Wob) {
  const int c0 = 2097152;            // X
  const int c1 = c0 + 4194304;       // Wq
  const int c2 = c1 + 1048576;       // Wk
  const int c3 = c2 + 1048576;       // Wv
  const int c4 = c3 + 4194304;       // Wo
  int i = blockIdx.x * blockDim.x + threadIdx.x;
  int stride = gridDim.x * blockDim.x;
  for (; i < c4; i += stride) {
    const float* src; unsigned short* dst; int off;
    if (i < c0)      { src = X;  dst = Xb;  off = i; }
    else if (i < c1) { src = Wq; dst = Wqb; off = i - c0; }
    else if (i < c2) { src = Wk; dst = Wkb; off = i - c1; }
    else if (i < c3) { src = Wv; dst = Wvb; off = i - c2; }
    else             { src = Wo; dst = Wob; off = i - c3; }
    float4 v = ((const float4*)src)[off];
    ushort4 o;
    o.x = f2bf(v.x); o.y = f2bf(v.y); o.z = f2bf(v.z); o.w = f2bf(v.w);
    ((ushort4*)dst)[off] = o;
  }
}

// ---------------- m97-structure GEMM core: C[m,n] = sum_k A[m,k]*B[n,k]
__device__ __forceinline__ void gemm_core(const unsigned short* __restrict__ A,
                                          const unsigned short* __restrict__ B,
                                          int K, unsigned short* ldsA, unsigned short* ldsB,
                                          int brow, int bcol, int tid, floatx4 acc[4][4]) {
  const int w = tid >> 6, lane = tid & 63;
  const int fr = lane & 15, fq = lane >> 4;
  const int wr = w >> 1, wc = w & 1;
  const unsigned short* pA = A + (size_t)(brow + (tid >> 2)) * K + (tid & 3) * 8;
  const unsigned short* pB = B + (size_t)(bcol + (tid >> 2)) * K + (tid & 3) * 8;
  const size_t rowHalf = (size_t)64 * K;
  unsigned short* lA = &ldsA[w * 512];
  unsigned short* lB = &ldsB[w * 512];

  int aoff[4], boff[4];
#pragma unroll
  for (int m = 0; m < 4; ++m) aoff[m] = (wr * 64 + m * 16 + fr) * 32 + fq * 8;
#pragma unroll
  for (int n = 0; n < 4; ++n) boff[n] = (wc * 64 + n * 16 + fr) * 32 + fq * 8;

  for (int k0 = 0; k0 < K; k0 += 32) {
    __syncthreads();
    gld_lds16(pA, lA);
    gld_lds16(pA + rowHalf, lA + 2048);
    gld_lds16(pB, lB);
    gld_lds16(pB + rowHalf, lB + 2048);
    pA += 32; pB += 32;
    asm volatile("s_waitcnt vmcnt(0)" ::: "memory");
    __syncthreads();
    short8v a[4], b[4];
#pragma unroll
    for (int m = 0; m < 4; ++m) a[m] = *(const short8v*)&ldsA[aoff[m]];
#pragma unroll
    for (int n = 0; n < 4; ++n) b[n] = *(const short8v*)&ldsB[boff[n]];
#pragma unroll
    for (int m = 0; m < 4; ++m)
#pragma unroll
      for (int n = 0; n < 4; ++n)
        acc[m][n] = __builtin_amdgcn_mfma_f32_16x16x32_bf16(a[m], b[n], acc[m][n], 0, 0, 0);
  }
}

// Fused QKV projection.
__global__ __launch_bounds__(256) void gemm_qkv(const unsigned short* __restrict__ Xb,
                                                const unsigned short* __restrict__ Wqb,
                                                const unsigned short* __restrict__ Wkb,
                                                const unsigned short* __restrict__ Wvb,
                                                unsigned short* __restrict__ Qg,
                                                unsigned short* __restrict__ Kg,
                                                unsigned short* __restrict__ Vt) {
  __shared__ unsigned short ldsA[128 * 32];
  __shared__ unsigned short ldsB[128 * 32];
  const int bx = blockIdx.x;
  const unsigned short* B; unsigned short* C; int mode, bcol, ldc;
  if (bx < 32)      { B = Wqb; C = Qg; mode = 0; bcol = bx * 128;        ldc = HID;  }
  else if (bx < 40) { B = Wkb; C = Kg; mode = 0; bcol = (bx - 32) * 128; ldc = 1024; }
  else              { B = Wvb; C = Vt; mode = 1; bcol = (bx - 40) * 128; ldc = 0;    }
  const int brow = blockIdx.y * 128;
  const int tid = threadIdx.x;
  floatx4 acc[4][4] = {};
  gemm_core(Xb, B, HID, ldsA, ldsB, brow, bcol, tid, acc);

  const int w = tid >> 6, lane = tid & 63;
  const int fr = lane & 15, fq = lane >> 4;
  const int r0 = brow + (w >> 1) * 64 + fq * 4;
  const int c0 = bcol + (w & 1) * 64 + fr;
  if (mode == 0) {
#pragma unroll
    for (int m = 0; m < 4; ++m)
#pragma unroll
      for (int n = 0; n < 4; ++n)
#pragma unroll
        for (int r = 0; r < 4; ++r)
          C[(size_t)(r0 + m * 16 + r) * ldc + c0 + n * 16] = f2bf(acc[m][n][r]);
  } else {
#pragma unroll
    for (int m = 0; m < 4; ++m)
#pragma unroll
      for (int n = 0; n < 4; ++n) {
        ushort4 pk;
        pk.x = f2bf(acc[m][n][0]); pk.y = f2bf(acc[m][n][1]);
        pk.z = f2bf(acc[m][n][2]); pk.w = f2bf(acc[m][n][3]);
        *(ushort4*)&C[(size_t)(c0 + n * 16) * S_LEN + (r0 + m * 16)] = pk;
      }
  }
}

// Output projection: f32 C to d_out.
__global__ __launch_bounds__(256) void gemm_o(const unsigned short* __restrict__ Ao,
                                              const unsigned short* __restrict__ Wob,
                                              float* __restrict__ Out) {
  __shared__ unsigned short ldsA[128 * 32];
  __shared__ unsigned short ldsB[128 * 32];
  const int tid = threadIdx.x;
  const int brow = blockIdx.y * 128, bcol = blockIdx.x * 128;
  floatx4 acc[4][4] = {};
  gemm_core(Ao, Wob, HID, ldsA, ldsB, brow, bcol, tid, acc);
  const int w = tid >> 6, lane = tid & 63;
  const int fr = lane & 15, fq = lane >> 4;
  const int r0 = brow + (w >> 1) * 64 + fq * 4;
  const int c0 = bcol + (w & 1) * 64 + fr;
#pragma unroll
  for (int m = 0; m < 4; ++m)
#pragma unroll
    for (int n = 0; n < 4; ++n)
#pragma unroll
      for (int r = 0; r < 4; ++r)
        Out[(size_t)(r0 + m * 16 + r) * HID + c0 + n * 16] = acc[m][n][r];
}

// ---------------- RoPE + per-head relayout ----------------
__global__ __launch_bounds__(256) void rope_kernel(const unsigned short* __restrict__ In,
                                                   const float* __restrict__ cosT,
                                                   const float* __restrict__ sinT,
                                                   unsigned short* __restrict__ Out,
                                                   int nh, float scale) {
  int idx = blockIdx.x * 256 + threadIdx.x;
  int j = idx & 63;
  int s = (idx >> 6) & (S_LEN - 1);
  int h = idx >> 17;
  unsigned int pr = *(const unsigned int*)(In + (size_t)s * (nh * HD) + h * HD + 2 * j);
  float q1 = bf2f((unsigned short)(pr & 0xffffu));
  float q2 = bf2f((unsigned short)(pr >> 16));
  float c = cosT[s * 64 + j], sn = sinT[s * 64 + j];
  unsigned short* op = Out + ((size_t)h * S_LEN + s) * HD + j;
  op[0]  = f2bf(scale * (q1 * c - q2 * sn));
  op[64] = f2bf(scale * (q2 * c + q1 * sn));
}

// ---------------- Flash attention, no K/V staging, no barriers ----------------
__global__ __launch_bounds__(256) void attn_fwd(const unsigned short* __restrict__ Qr,
                                                const unsigned short* __restrict__ Kr,
                                                const unsigned short* __restrict__ Vt,
                                                unsigned short* __restrict__ Ao) {
  __shared__ unsigned short Pl[4][16 * 72];
  const int id = blockIdx.x;
  const int swz = (id & 7) * 128 + (id >> 3);   // XCD c <-> kv-head c
  const int h  = swz >> 5;
  const int qt = 31 - (swz & 31);               // heavy blocks first
  const int hk = h >> 2;
  const int qb = qt * 64;
  const int tid = threadIdx.x, w = tid >> 6, lane = tid & 63;
  const int fr = lane & 15, fq = lane >> 4;

  short8v aq[4];
  {
    const unsigned short* qp = Qr + ((size_t)(h * S_LEN + qb + w * 16 + fr)) * HD + fq * 8;
#pragma unroll
    for (int ks = 0; ks < 4; ++ks) aq[ks] = *(const short8v*)(qp + ks * 32);
  }

  const unsigned short* kbase = Kr + ((size_t)hk * S_LEN + fr) * HD + fq * 8;
  const unsigned short* vbase = Vt + ((size_t)hk * HD + fr) * S_LEN + fq * 8;

  float m_r[4] = {-1e30f, -1e30f, -1e30f, -1e30f};
  float l_r[4] = {0.f, 0.f, 0.f, 0.f};
  floatx4 o[8] = {};

  for (int t = 0; t <= qt; ++t) {
    const int kv0 = t * 64;

    floatx4 s4[4] = {};
    const unsigned short* kp = kbase + (size_t)kv0 * HD;
#pragma unroll
    for (int ks = 0; ks < 4; ++ks) {
      short8v bk[4];
#pragma unroll
      for (int n = 0; n < 4; ++n) bk[n] = *(const short8v*)(kp + (size_t)(n * 16) * HD + ks * 32);
#pragma unroll
      for (int n = 0; n < 4; ++n)
        s4[n] = __builtin_amdgcn_mfma_f32_16x16x32_bf16(aq[ks], bk[n], s4[n], 0, 0, 0);
    }

    if (t == qt) {
#pragma unroll
      for (int n = 0; n < 4; ++n) {
        int col = kv0 + n * 16 + fr;
#pragma unroll
        for (int r = 0; r < 4; ++r) {
          int rowq = qb + w * 16 + fq * 4 + r;
          if (col > rowq) s4[n][r] = -1e30f;
        }
      }
    }

    float vmax[4];
#pragma unroll
    for (int r = 0; r < 4; ++r)
      vmax[r] = fmaxf(fmaxf(s4[0][r], s4[1][r]), fmaxf(s4[2][r], s4[3][r]));
#pragma unroll
    for (int off = 8; off; off >>= 1)
#pragma unroll
      for (int r = 0; r < 4; ++r)
        vmax[r] = fmaxf(vmax[r], __shfl_xor(vmax[r], off));

    float alpha[4], psum[4] = {0.f, 0.f, 0.f, 0.f};
#pragma unroll
    for (int r = 0; r < 4; ++r) {
      float mn = fmaxf(m_r[r], vmax[r]);
      alpha[r] = __expf(m_r[r] - mn);
      m_r[r] = mn;
    }
#pragma unroll
    for (int n = 0; n < 4; ++n)
#pragma unroll
      for (int r = 0; r < 4; ++r) {
        float p = __expf(s4[n][r] - m_r[r]);
        psum[r] += p;
        Pl[w][(fq * 4 + r) * 72 + n * 16 + fr] = f2bf(p);
      }
#pragma unroll
    for (int r = 0; r < 4; ++r) l_r[r] = l_r[r] * alpha[r] + psum[r];
#pragma unroll
    for (int nf = 0; nf < 8; ++nf)
#pragma unroll
      for (int r = 0; r < 4; ++r) o[nf][r] *= alpha[r];

    short8v pa[2];
#pragma unroll
    for (int ks = 0; ks < 2; ++ks)
      pa[ks] = *(const short8v*)&Pl[w][fr * 72 + ks * 32 + fq * 8];
    const unsigned short* vp = vbase + kv0;
#pragma unroll
    for (int nf = 0; nf < 8; ++nf) {
#pragma unroll
      for (int ks = 0; ks < 2; ++ks) {
        short8v bv = *(const short8v*)(vp + (size_t)(nf * 16) * S_LEN + ks * 32);
        o[nf] = __builtin_amdgcn_mfma_f32_16x16x32_bf16(pa[ks], bv, o[nf], 0, 0, 0);
      }
    }
  }

  float lsum[4];
#pragma unroll
  for (int r = 0; r < 4; ++r) lsum[r] = l_r[r];
#pragma unroll
  for (int off = 8; off; off >>= 1)
#pragma unroll
    for (int r = 0; r < 4; ++r) lsum[r] += __shfl_xor(lsum[r], off);
  float rinv[4];
#pragma unroll
  for (int r = 0; r < 4; ++r) rinv[r] = 1.0f / lsum[r];

  unsigned short* aop = Ao + (size_t)(qb + w * 16 + fq * 4) * HID + h * HD + fr;
#pragma unroll
  for (int nf = 0; nf < 8; ++nf)
#pragma unroll
    for (int r = 0; r < 4; ++r)
      aop[(size_t)r * HID + nf * 16] = f2bf(o[nf][r] * rinv[r]);
}

// ---------------- launch ----------------
extern "C" void kernel_launch(void* const* d_in, const int* in_sizes, int n_in,
                              void* d_out, int out_size, void* d_ws, size_t ws_size,
                              hipStream_t stream) {
  (void)in_sizes; (void)n_in; (void)out_size; (void)ws_size;
  const float* X    = (const float*)d_in[0];
  const float* cosT = (const float*)d_in[3];
  const float* sinT = (const float*)d_in[4];
  const float* Wq   = (const float*)d_in[5];
  const float* Wk   = (const float*)d_in[6];
  const float* Wv   = (const float*)d_in[7];
  const float* Wo   = (const float*)d_in[8];

  char* ws = (char*)d_ws;
  size_t off = 0;
  auto alloc = [&](size_t bytes) { char* p = ws + off; off += (bytes + 255) & ~(size_t)255; return p; };
  unsigned short* Xb  = (unsigned short*)alloc((size_t)S_LEN * HID * 2);
  unsigned short* Wqb = (unsigned short*)alloc((size_t)HID * HID * 2);
  unsigned short* Wkb = (unsigned short*)alloc((size_t)1024 * HID * 2);
  unsigned short* Wvb = (unsigned short*)alloc((size_t)1024 * HID * 2);
  unsigned short* Wob = (unsigned short*)alloc((size_t)HID * HID * 2);
  unsigned short* Qg  = (unsigned short*)alloc((size_t)S_LEN * HID * 2);
  unsigned short* Kg  = (unsigned short*)alloc((size_t)S_LEN * 1024 * 2);
  unsigned short* Vt  = (unsigned short*)alloc((size_t)1024 * S_LEN * 2);
  unsigned short* Qr = Wqb;                              // aliases, stream-ordered lifetimes
  unsigned short* Kr = Wqb + (size_t)NH * S_LEN * HD;
  unsigned short* Ao = Xb;

  cvt_all<<<2048, 256, 0, stream>>>(X, Wq, Wk, Wv, Wo, Xb, Wqb, Wkb, Wvb, Wob);
  gemm_qkv<<<dim3(48, 16), 256, 0, stream>>>(Xb, Wqb, Wkb, Wvb, Qg, Kg, Vt);
  rope_kernel<<<(NH * S_LEN * 64) / 256, 256, 0, stream>>>(Qg, cosT, sinT, Qr, NH, 0.08838834764831845f);
  rope_kernel<<<(NKV * S_LEN * 64) / 256, 256, 0, stream>>>(Kg, cosT, sinT, Kr, NKV, 1.0f);
  attn_fwd<<<1024, 256, 0, stream>>>(Qr, Kr, Vt, Ao);
  gemm_o<<<dim3(32, 16), 256, 0, stream>>>(Ao, Wob, (float*)d_out);
}

// Round 3
// 425.813 us; speedup vs baseline: 1.5607x; 1.5607x over previous
//
#include <hip/hip_runtime.h>
#include <hip/hip_bf16.h>

#define S_LEN 2048
#define HID   4096
#define NH    32
#define NKV   8
#define HD    128

typedef __attribute__((ext_vector_type(8))) short short8v;
typedef __attribute__((ext_vector_type(4))) float floatx4;

__device__ __forceinline__ float bf2f(unsigned short u) {
  union { unsigned int u32; float f; } v; v.u32 = ((unsigned int)u) << 16; return v.f;
}
__device__ __forceinline__ unsigned short f2bf(float f) {
  union { float f; unsigned int u; } v; v.f = f;
  unsigned int u = v.u + 0x7fffu + ((v.u >> 16) & 1u);
  return (unsigned short)(u >> 16);
}

__device__ __forceinline__ void gld_lds16(const void* g, void* l) {
  __builtin_amdgcn_global_load_lds((const __attribute__((address_space(1))) void*)g,
                                   (__attribute__((address_space(3))) void*)l, 16, 0, 0);
}

// ---------------- fused f32 -> bf16 convert for all 5 tensors ----------------
__global__ __launch_bounds__(256) void cvt_all(const float* __restrict__ X,  const float* __restrict__ Wq,
                                               const float* __restrict__ Wk, const float* __restrict__ Wv,
                                               const float* __restrict__ Wo,
                                               unsigned short* __restrict__ Xb,  unsigned short* __restrict__ Wqb,
                                               unsigned short* __restrict__ Wkb, unsigned short* __restrict__ Wvb,
                                               unsigned short* __restrict__ Wob) {
  const int c0 = 2097152;            // X
  const int c1 = c0 + 4194304;       // Wq
  const int c2 = c1 + 1048576;       // Wk
  const int c3 = c2 + 1048576;       // Wv
  const int c4 = c3 + 4194304;       // Wo
  int i = blockIdx.x * blockDim.x + threadIdx.x;
  int stride = gridDim.x * blockDim.x;
  for (; i < c4; i += stride) {
    const float* src; unsigned short* dst; int off;
    if (i < c0)      { src = X;  dst = Xb;  off = i; }
    else if (i < c1) { src = Wq; dst = Wqb; off = i - c0; }
    else if (i < c2) { src = Wk; dst = Wkb; off = i - c1; }
    else if (i < c3) { src = Wv; dst = Wvb; off = i - c2; }
    else             { src = Wo; dst = Wob; off = i - c3; }
    float4 v = ((const float4*)src)[off];
    ushort4 o;
    o.x = f2bf(v.x); o.y = f2bf(v.y); o.z = f2bf(v.z); o.w = f2bf(v.w);
    ((ushort4*)dst)[off] = o;
  }
}

// ---------------- m97-structure GEMM core: C[m,n] = sum_k A[m,k]*B[n,k]
__device__ __forceinline__ void gemm_core(const unsigned short* __restrict__ A,
                                          const unsigned short* __restrict__ B,
                                          int K, unsigned short* ldsA, unsigned short* ldsB,
                                          int brow, int bcol, int tid, floatx4 acc[4][4]) {
  const int w = tid >> 6, lane = tid & 63;
  const int fr = lane & 15, fq = lane >> 4;
  const int wr = w >> 1, wc = w & 1;
  const unsigned short* pA = A + (size_t)(brow + (tid >> 2)) * K + (tid & 3) * 8;
  const unsigned short* pB = B + (size_t)(bcol + (tid >> 2)) * K + (tid & 3) * 8;
  const size_t rowHalf = (size_t)64 * K;
  unsigned short* lA = &ldsA[w * 512];
  unsigned short* lB = &ldsB[w * 512];

  int aoff[4], boff[4];
#pragma unroll
  for (int m = 0; m < 4; ++m) aoff[m] = (wr * 64 + m * 16 + fr) * 32 + fq * 8;
#pragma unroll
  for (int n = 0; n < 4; ++n) boff[n] = (wc * 64 + n * 16 + fr) * 32 + fq * 8;

  for (int k0 = 0; k0 < K; k0 += 32) {
    __syncthreads();
    gld_lds16(pA, lA);
    gld_lds16(pA + rowHalf, lA + 2048);
    gld_lds16(pB, lB);
    gld_lds16(pB + rowHalf, lB + 2048);
    pA += 32; pB += 32;
    asm volatile("s_waitcnt vmcnt(0)" ::: "memory");
    __syncthreads();
    short8v a[4], b[4];
#pragma unroll
    for (int m = 0; m < 4; ++m) a[m] = *(const short8v*)&ldsA[aoff[m]];
#pragma unroll
    for (int n = 0; n < 4; ++n) b[n] = *(const short8v*)&ldsB[boff[n]];
#pragma unroll
    for (int m = 0; m < 4; ++m)
#pragma unroll
      for (int n = 0; n < 4; ++n)
        acc[m][n] = __builtin_amdgcn_mfma_f32_16x16x32_bf16(a[m], b[n], acc[m][n], 0, 0, 0);
  }
}

// Fused QKV projection.
__global__ __launch_bounds__(256) void gemm_qkv(const unsigned short* __restrict__ Xb,
                                                const unsigned short* __restrict__ Wqb,
                                                const unsigned short* __restrict__ Wkb,
                                                const unsigned short* __restrict__ Wvb,
                                                unsigned short* __restrict__ Qg,
                                                unsigned short* __restrict__ Kg,
                                                unsigned short* __restrict__ Vt) {
  __shared__ unsigned short ldsA[128 * 32];
  __shared__ unsigned short ldsB[128 * 32];
  const int bx = blockIdx.x;
  const unsigned short* B; unsigned short* C; int mode, bcol, ldc;
  if (bx < 32)      { B = Wqb; C = Qg; mode = 0; bcol = bx * 128;        ldc = HID;  }
  else if (bx < 40) { B = Wkb; C = Kg; mode = 0; bcol = (bx - 32) * 128; ldc = 1024; }
  else              { B = Wvb; C = Vt; mode = 1; bcol = (bx - 40) * 128; ldc = 0;    }
  const int brow = blockIdx.y * 128;
  const int tid = threadIdx.x;
  floatx4 acc[4][4] = {};
  gemm_core(Xb, B, HID, ldsA, ldsB, brow, bcol, tid, acc);

  const int w = tid >> 6, lane = tid & 63;
  const int fr = lane & 15, fq = lane >> 4;
  const int r0 = brow + (w >> 1) * 64 + fq * 4;
  const int c0 = bcol + (w & 1) * 64 + fr;
  if (mode == 0) {
#pragma unroll
    for (int m = 0; m < 4; ++m)
#pragma unroll
      for (int n = 0; n < 4; ++n)
#pragma unroll
        for (int r = 0; r < 4; ++r)
          C[(size_t)(r0 + m * 16 + r) * ldc + c0 + n * 16] = f2bf(acc[m][n][r]);
  } else {
#pragma unroll
    for (int m = 0; m < 4; ++m)
#pragma unroll
      for (int n = 0; n < 4; ++n) {
        ushort4 pk;
        pk.x = f2bf(acc[m][n][0]); pk.y = f2bf(acc[m][n][1]);
        pk.z = f2bf(acc[m][n][2]); pk.w = f2bf(acc[m][n][3]);
        *(ushort4*)&C[(size_t)(c0 + n * 16) * S_LEN + (r0 + m * 16)] = pk;
      }
  }
}

// Output projection: f32 C to d_out.
__global__ __launch_bounds__(256) void gemm_o(const unsigned short* __restrict__ Ao,
                                              const unsigned short* __restrict__ Wob,
                                              float* __restrict__ Out) {
  __shared__ unsigned short ldsA[128 * 32];
  __shared__ unsigned short ldsB[128 * 32];
  const int tid = threadIdx.x;
  const int brow = blockIdx.y * 128, bcol = blockIdx.x * 128;
  floatx4 acc[4][4] = {};
  gemm_core(Ao, Wob, HID, ldsA, ldsB, brow, bcol, tid, acc);
  const int w = tid >> 6, lane = tid & 63;
  const int fr = lane & 15, fq = lane >> 4;
  const int r0 = brow + (w >> 1) * 64 + fq * 4;
  const int c0 = bcol + (w & 1) * 64 + fr;
#pragma unroll
  for (int m = 0; m < 4; ++m)
#pragma unroll
    for (int n = 0; n < 4; ++n)
#pragma unroll
      for (int r = 0; r < 4; ++r)
        Out[(size_t)(r0 + m * 16 + r) * HID + c0 + n * 16] = acc[m][n][r];
}

// ---------------- RoPE + per-head relayout ----------------
__global__ __launch_bounds__(256) void rope_kernel(const unsigned short* __restrict__ In,
                                                   const float* __restrict__ cosT,
                                                   const float* __restrict__ sinT,
                                                   unsigned short* __restrict__ Out,
                                                   int nh, float scale) {
  int idx = blockIdx.x * 256 + threadIdx.x;
  int j = idx & 63;
  int s = (idx >> 6) & (S_LEN - 1);
  int h = idx >> 17;
  unsigned int pr = *(const unsigned int*)(In + (size_t)s * (nh * HD) + h * HD + 2 * j);
  float q1 = bf2f((unsigned short)(pr & 0xffffu));
  float q2 = bf2f((unsigned short)(pr >> 16));
  float c = cosT[s * 64 + j], sn = sinT[s * 64 + j];
  unsigned short* op = Out + ((size_t)h * S_LEN + s) * HD + j;
  op[0]  = f2bf(scale * (q1 * c - q2 * sn));
  op[64] = f2bf(scale * (q2 * c + q1 * sn));
}

// ---------------- Flash attention: LDS-staged K/V, DOUBLE-BUFFERED 2-phase.
// Per tile: issue STAGE(next) BEFORE compute(cur); one vmcnt(0)+barrier at end.
// K/V rows XOR-swizzled via pre-swizzled global source (linear gld_lds dest).
// Grid 1024 (1-D), XCD c <-> kv-head c, heavy (high-qt) blocks first.
__global__ __launch_bounds__(256) void attn_fwd(const unsigned short* __restrict__ Qr,
                                                const unsigned short* __restrict__ Kr,
                                                const unsigned short* __restrict__ Vt,
                                                unsigned short* __restrict__ Ao) {
  __shared__ unsigned short Kl[2][64 * 128];  // [kv][128], swizzled (cb ^ (row&7)<<4)
  __shared__ unsigned short Vl[2][64 * 128];  // [d][kv] 128 rows x 64, swizzled
  __shared__ unsigned short Pl[4][16 * 72];   // per-wave P [16 q][64 kv], stride 72
  const int id = blockIdx.x;
  const int swz = (id & 7) * 128 + (id >> 3);   // XCD-chunked, bijective (1024 = 8*128)
  const int h  = swz >> 5;                      // 4 consecutive heads per XCD = 1 kv-head
  const int qt = 31 - (swz & 31);               // heavy blocks first
  const int hk = h >> 2;
  const int qb = qt * 64;
  const int tid = threadIdx.x, w = tid >> 6, lane = tid & 63;
  const int fr = lane & 15, fq = lane >> 4;

  // Q fragments (A-operand): rows qb+w*16+fr, k = ks*32+fq*8. Q pre-scaled 1/sqrt(128).
  short8v aq[4];
  {
    const unsigned short* qp = Qr + ((size_t)(h * S_LEN + qb + w * 16 + fr)) * HD + fq * 8;
#pragma unroll
    for (int ks = 0; ks < 4; ++ks) aq[ks] = *(const short8v*)(qp + ks * 32);
  }

  // staging sources (pre-swizzled global byte offset, linear LDS dest)
  const int kcb = ((tid & 15) * 16) ^ (((tid >> 4) & 7) << 4);
  const unsigned short* pK0 = Kr + ((size_t)hk * S_LEN + (tid >> 4)) * HD + (kcb >> 1);
  const int vcb = ((tid & 7) * 16) ^ (((tid >> 3) & 7) << 4);
  const unsigned short* pV0 = Vt + ((size_t)hk * HD + (tid >> 3)) * S_LEN + (vcb >> 1);

  float m_r[4] = {-1e30f, -1e30f, -1e30f, -1e30f};
  float l_r[4] = {0.f, 0.f, 0.f, 0.f};
  floatx4 o[8] = {};

#define STAGE(buf, t)                                                          \
  do {                                                                         \
    const unsigned short* pk_ = pK0 + (size_t)(t) * 64 * HD;                   \
    const unsigned short* pv_ = pV0 + (t) * 64;                                \
    _Pragma("unroll")                                                          \
    for (int j = 0; j < 4; ++j)                                                \
      gld_lds16(pk_ + (size_t)j * 16 * HD, &Kl[buf][w * 512 + j * 2048]);      \
    _Pragma("unroll")                                                          \
    for (int j = 0; j < 4; ++j)                                                \
      gld_lds16(pv_ + (size_t)j * 32 * S_LEN, &Vl[buf][w * 512 + j * 2048]);   \
  } while (0)

  STAGE(0, 0);
  asm volatile("s_waitcnt vmcnt(0)" ::: "memory");
  __syncthreads();

  int cur = 0;
  for (int t = 0; t <= qt; ++t) {
    const int kv0 = t * 64;
    if (t < qt) STAGE(cur ^ 1, t + 1);   // overlap next-tile staging with compute

    // S = Q K^T  (16 x 64 per wave)
    floatx4 s4[4] = {};
    const unsigned short* Kc = &Kl[cur][0];
    const unsigned short* Vc = &Vl[cur][0];
#pragma unroll
    for (int ks = 0; ks < 4; ++ks) {
#pragma unroll
      for (int n = 0; n < 4; ++n) {
        int row = n * 16 + fr;
        int cb = (ks * 64 + fq * 16) ^ ((row & 7) << 4);
        short8v bk = *(const short8v*)&Kc[row * 128 + (cb >> 1)];
        s4[n] = __builtin_amdgcn_mfma_f32_16x16x32_bf16(aq[ks], bk, s4[n], 0, 0, 0);
      }
    }

    if (t == qt) {  // diagonal tile: causal mask
#pragma unroll
      for (int n = 0; n < 4; ++n) {
        int col = kv0 + n * 16 + fr;
#pragma unroll
        for (int r = 0; r < 4; ++r) {
          int rowq = qb + w * 16 + fq * 4 + r;
          if (col > rowq) s4[n][r] = -1e30f;
        }
      }
    }

    // online softmax (row = fq*4+r, cols across fr)
    float vmax[4];
#pragma unroll
    for (int r = 0; r < 4; ++r)
      vmax[r] = fmaxf(fmaxf(s4[0][r], s4[1][r]), fmaxf(s4[2][r], s4[3][r]));
#pragma unroll
    for (int off = 8; off; off >>= 1)
#pragma unroll
      for (int r = 0; r < 4; ++r)
        vmax[r] = fmaxf(vmax[r], __shfl_xor(vmax[r], off));

    float alpha[4], psum[4] = {0.f, 0.f, 0.f, 0.f};
#pragma unroll
    for (int r = 0; r < 4; ++r) {
      float mn = fmaxf(m_r[r], vmax[r]);
      alpha[r] = __expf(m_r[r] - mn);
      m_r[r] = mn;
    }
#pragma unroll
    for (int n = 0; n < 4; ++n)
#pragma unroll
      for (int r = 0; r < 4; ++r) {
        float p = __expf(s4[n][r] - m_r[r]);
        psum[r] += p;
        Pl[w][(fq * 4 + r) * 72 + n * 16 + fr] = f2bf(p);
      }
#pragma unroll
    for (int r = 0; r < 4; ++r) l_r[r] = l_r[r] * alpha[r] + psum[r];
#pragma unroll
    for (int nf = 0; nf < 8; ++nf)
#pragma unroll
      for (int r = 0; r < 4; ++r) o[nf][r] *= alpha[r];

    // O += P V  (P via per-wave LDS transpose; V from staged LDS)
    short8v pa[2];
#pragma unroll
    for (int ks = 0; ks < 2; ++ks)
      pa[ks] = *(const short8v*)&Pl[w][fr * 72 + ks * 32 + fq * 8];
#pragma unroll
    for (int nf = 0; nf < 8; ++nf) {
#pragma unroll
      for (int ks = 0; ks < 2; ++ks) {
        int row = nf * 16 + fr;
        int cb = (ks * 64 + fq * 16) ^ ((row & 7) << 4);
        short8v bv = *(const short8v*)&Vc[row * 64 + (cb >> 1)];
        o[nf] = __builtin_amdgcn_mfma_f32_16x16x32_bf16(pa[ks], bv, o[nf], 0, 0, 0);
      }
    }

    if (t < qt) {
      asm volatile("s_waitcnt vmcnt(0)" ::: "memory");  // next tile staged (overlapped)
      __syncthreads();
      cur ^= 1;
    }
  }
#undef STAGE

  // normalize + write Ao[s][h*128+d]
  float lsum[4];
#pragma unroll
  for (int r = 0; r < 4; ++r) lsum[r] = l_r[r];
#pragma unroll
  for (int off = 8; off; off >>= 1)
#pragma unroll
    for (int r = 0; r < 4; ++r) lsum[r] += __shfl_xor(lsum[r], off);
  float rinv[4];
#pragma unroll
  for (int r = 0; r < 4; ++r) rinv[r] = 1.0f / lsum[r];

  unsigned short* aop = Ao + (size_t)(qb + w * 16 + fq * 4) * HID + h * HD + fr;
#pragma unroll
  for (int nf = 0; nf < 8; ++nf)
#pragma unroll
    for (int r = 0; r < 4; ++r)
      aop[(size_t)r * HID + nf * 16] = f2bf(o[nf][r] * rinv[r]);
}

// ---------------- launch ----------------
extern "C" void kernel_launch(void* const* d_in, const int* in_sizes, int n_in,
                              void* d_out, int out_size, void* d_ws, size_t ws_size,
                              hipStream_t stream) {
  (void)in_sizes; (void)n_in; (void)out_size; (void)ws_size;
  const float* X    = (const float*)d_in[0];
  const float* cosT = (const float*)d_in[3];
  const float* sinT = (const float*)d_in[4];
  const float* Wq   = (const float*)d_in[5];
  const float* Wk   = (const float*)d_in[6];
  const float* Wv   = (const float*)d_in[7];
  const float* Wo   = (const float*)d_in[8];

  char* ws = (char*)d_ws;
  size_t off = 0;
  auto alloc = [&](size_t bytes) { char* p = ws + off; off += (bytes + 255) & ~(size_t)255; return p; };
  unsigned short* Xb  = (unsigned short*)alloc((size_t)S_LEN * HID * 2);
  unsigned short* Wqb = (unsigned short*)alloc((size_t)HID * HID * 2);
  unsigned short* Wkb = (unsigned short*)alloc((size_t)1024 * HID * 2);
  unsigned short* Wvb = (unsigned short*)alloc((size_t)1024 * HID * 2);
  unsigned short* Wob = (unsigned short*)alloc((size_t)HID * HID * 2);
  unsigned short* Qg  = (unsigned short*)alloc((size_t)S_LEN * HID * 2);
  unsigned short* Kg  = (unsigned short*)alloc((size_t)S_LEN * 1024 * 2);
  unsigned short* Vt  = (unsigned short*)alloc((size_t)1024 * S_LEN * 2);
  unsigned short* Qr = Wqb;                              // aliases, stream-ordered lifetimes
  unsigned short* Kr = Wqb + (size_t)NH * S_LEN * HD;
  unsigned short* Ao = Xb;

  cvt_all<<<2048, 256, 0, stream>>>(X, Wq, Wk, Wv, Wo, Xb, Wqb, Wkb, Wvb, Wob);
  gemm_qkv<<<dim3(48, 16), 256, 0, stream>>>(Xb, Wqb, Wkb, Wvb, Qg, Kg, Vt);
  rope_kernel<<<(NH * S_LEN * 64) / 256, 256, 0, stream>>>(Qg, cosT, sinT, Qr, NH, 0.08838834764831845f);
  rope_kernel<<<(NKV * S_LEN * 64) / 256, 256, 0, stream>>>(Kg, cosT, sinT, Kr, NKV, 1.0f);
  attn_fwd<<<1024, 256, 0, stream>>>(Qr, Kr, Vt, Ao);
  gemm_o<<<dim3(32, 16), 256, 0, stream>>>(Ao, Wob, (float*)d_out);
}

// Round 4
// 364.208 us; speedup vs baseline: 1.8247x; 1.1691x over previous
//
#include <hip/hip_runtime.h>
#include <hip/hip_bf16.h>

#define S_LEN 2048
#define HID   4096
#define NH    32
#define NKV   8
#define HD    128

typedef __attribute__((ext_vector_type(8))) short short8v;
typedef __attribute__((ext_vector_type(4))) float floatx4;

__device__ __forceinline__ float bf2f(unsigned short u) {
  union { unsigned int u32; float f; } v; v.u32 = ((unsigned int)u) << 16; return v.f;
}
__device__ __forceinline__ unsigned short f2bf(float f) {
  union { float f; unsigned int u; } v; v.f = f;
  unsigned int u = v.u + 0x7fffu + ((v.u >> 16) & 1u);
  return (unsigned short)(u >> 16);
}

__device__ __forceinline__ void gld_lds16(const void* g, void* l) {
  __builtin_amdgcn_global_load_lds((const __attribute__((address_space(1))) void*)g,
                                   (__attribute__((address_space(3))) void*)l, 16, 0, 0);
}

// ---------------- fused f32 -> bf16 convert for all 5 tensors ----------------
__global__ __launch_bounds__(256) void cvt_all(const float* __restrict__ X,  const float* __restrict__ Wq,
                                               const float* __restrict__ Wk, const float* __restrict__ Wv,
                                               const float* __restrict__ Wo,
                                               unsigned short* __restrict__ Xb,  unsigned short* __restrict__ Wqb,
                                               unsigned short* __restrict__ Wkb, unsigned short* __restrict__ Wvb,
                                               unsigned short* __restrict__ Wob) {
  const int c0 = 2097152;            // X
  const int c1 = c0 + 4194304;       // Wq
  const int c2 = c1 + 1048576;       // Wk
  const int c3 = c2 + 1048576;       // Wv
  const int c4 = c3 + 4194304;       // Wo
  int i = blockIdx.x * blockDim.x + threadIdx.x;
  int stride = gridDim.x * blockDim.x;
  for (; i < c4; i += stride) {
    const float* src; unsigned short* dst; int off;
    if (i < c0)      { src = X;  dst = Xb;  off = i; }
    else if (i < c1) { src = Wq; dst = Wqb; off = i - c0; }
    else if (i < c2) { src = Wk; dst = Wkb; off = i - c1; }
    else if (i < c3) { src = Wv; dst = Wvb; off = i - c2; }
    else             { src = Wo; dst = Wob; off = i - c3; }
    float4 v = ((const float4*)src)[off];
    ushort4 o;
    o.x = f2bf(v.x); o.y = f2bf(v.y); o.z = f2bf(v.z); o.w = f2bf(v.w);
    ((ushort4*)dst)[off] = o;
  }
}

// ---------------- Pipelined GEMM core: C[m,n] = sum_k A[m,k]*B[n,k], K=4096.
// Tile 256(M) x 128(N), BK=32, 512 thr = 8 waves (4M x 2N), per-wave 64x64.
// 3 LDS buffers (24 KB each, 72 KB total -> 2 blocks/CU). Depth-2 prefetch:
// iter t stages tile t+2, computes tile t, vmcnt(3) (counted, never 0) + 1 barrier.
// LDS rows (64 B) XOR-swizzled (slot ^= row&3) via pre-swizzled global source.
__device__ __forceinline__ void gemm_pipe_core(const unsigned short* __restrict__ A,
                                               const unsigned short* __restrict__ B,
                                               unsigned short* lds,
                                               int brow, int bcol, int tid,
                                               floatx4 acc[4][4]) {
  const int K = 4096;
  const int w = tid >> 6, lane = tid & 63;
  const int fr = lane & 15, fq = lane >> 4;
  const int wm = w >> 1, wn = w & 1;

  // staging sources (pre-swizzled column so swizzled read returns true layout)
  const int rA0 = tid >> 2, sA = tid & 3;
  const unsigned short* pA0 = A + (size_t)(brow + rA0) * K       + ((sA ^ (rA0 & 3)) << 3);
  const unsigned short* pA1 = A + (size_t)(brow + 128 + rA0) * K + ((sA ^ (rA0 & 3)) << 3);
  const unsigned short* pB0 = B + (size_t)(bcol + rA0) * K       + ((sA ^ (rA0 & 3)) << 3);

  // ds_read offsets (shorts). A at buf+0 (256x32), B at buf+8192 (128x32).
  const int sl = (fq ^ (fr & 3)) << 3;   // swizzled 8-elem slot within 64B row
  int aoff[4], boff[4];
#pragma unroll
  for (int m = 0; m < 4; ++m) aoff[m] = (wm * 64 + m * 16 + fr) * 32 + sl;
#pragma unroll
  for (int n = 0; n < 4; ++n) boff[n] = 8192 + (wn * 64 + n * 16 + fr) * 32 + sl;

#define STAGEG(buf, kofs)                                        \
  do {                                                           \
    unsigned short* b_ = lds + (buf) * 12288 + w * 512;          \
    gld_lds16(pA0 + (kofs), b_);                                 \
    gld_lds16(pA1 + (kofs), b_ + 4096);                          \
    gld_lds16(pB0 + (kofs), b_ + 8192);                          \
  } while (0)

  STAGEG(0, 0);
  STAGEG(1, 32);
  asm volatile("s_waitcnt vmcnt(3)" ::: "memory");   // tile 0 landed
  __syncthreads();

  int cb = 0, nb = 2;
  for (int t = 0; t < 128; ++t) {
    if (t + 2 < 128) STAGEG(nb, (t + 2) * 32);

    const unsigned short* Lc = lds + cb * 12288;
    short8v a[4], b[4];
#pragma unroll
    for (int m = 0; m < 4; ++m) a[m] = *(const short8v*)&Lc[aoff[m]];
#pragma unroll
    for (int n = 0; n < 4; ++n) b[n] = *(const short8v*)&Lc[boff[n]];

    __builtin_amdgcn_s_setprio(1);
#pragma unroll
    for (int m = 0; m < 4; ++m)
#pragma unroll
      for (int n = 0; n < 4; ++n)
        acc[m][n] = __builtin_amdgcn_mfma_f32_16x16x32_bf16(a[m], b[n], acc[m][n], 0, 0, 0);
    __builtin_amdgcn_s_setprio(0);

    if (t + 1 < 128) {
      if (t + 2 < 128) asm volatile("s_waitcnt vmcnt(3)" ::: "memory");  // t+1 landed
      else             asm volatile("s_waitcnt vmcnt(0)" ::: "memory");  // epilogue drain
      __syncthreads();
      cb = (cb == 2) ? 0 : cb + 1;
      nb = (nb == 2) ? 0 : nb + 1;
    }
  }
#undef STAGEG
}

// Fused QKV projection. Grid (48, 8): bx<32 Q, 32..39 K, 40..47 V(transposed out).
__global__ __launch_bounds__(512, 4) void gemm_qkv(const unsigned short* __restrict__ Xb,
                                                   const unsigned short* __restrict__ Wqb,
                                                   const unsigned short* __restrict__ Wkb,
                                                   const unsigned short* __restrict__ Wvb,
                                                   unsigned short* __restrict__ Qg,
                                                   unsigned short* __restrict__ Kg,
                                                   unsigned short* __restrict__ Vt) {
  __shared__ unsigned short lds[3 * 12288];
  const int bx = blockIdx.x;
  const unsigned short* B; unsigned short* C; int mode, bcol, ldc;
  if (bx < 32)      { B = Wqb; C = Qg; mode = 0; bcol = bx * 128;        ldc = HID;  }
  else if (bx < 40) { B = Wkb; C = Kg; mode = 0; bcol = (bx - 32) * 128; ldc = 1024; }
  else              { B = Wvb; C = Vt; mode = 1; bcol = (bx - 40) * 128; ldc = 0;    }
  const int brow = blockIdx.y * 256;
  const int tid = threadIdx.x;
  floatx4 acc[4][4] = {};
  gemm_pipe_core(Xb, B, lds, brow, bcol, tid, acc);

  const int w = tid >> 6, lane = tid & 63;
  const int fr = lane & 15, fq = lane >> 4;
  const int r0 = brow + (w >> 1) * 64 + fq * 4;
  const int c0 = bcol + (w & 1) * 64 + fr;
  if (mode == 0) {
#pragma unroll
    for (int m = 0; m < 4; ++m)
#pragma unroll
      for (int n = 0; n < 4; ++n)
#pragma unroll
        for (int r = 0; r < 4; ++r)
          C[(size_t)(r0 + m * 16 + r) * ldc + c0 + n * 16] = f2bf(acc[m][n][r]);
  } else {
#pragma unroll
    for (int m = 0; m < 4; ++m)
#pragma unroll
      for (int n = 0; n < 4; ++n) {
        ushort4 pk;
        pk.x = f2bf(acc[m][n][0]); pk.y = f2bf(acc[m][n][1]);
        pk.z = f2bf(acc[m][n][2]); pk.w = f2bf(acc[m][n][3]);
        *(ushort4*)&C[(size_t)(c0 + n * 16) * S_LEN + (r0 + m * 16)] = pk;
      }
  }
}

// Output projection: f32 C to d_out. Grid (32, 8).
__global__ __launch_bounds__(512, 4) void gemm_o(const unsigned short* __restrict__ Ao,
                                                 const unsigned short* __restrict__ Wob,
                                                 float* __restrict__ Out) {
  __shared__ unsigned short lds[3 * 12288];
  const int tid = threadIdx.x;
  const int brow = blockIdx.y * 256, bcol = blockIdx.x * 128;
  floatx4 acc[4][4] = {};
  gemm_pipe_core(Ao, Wob, lds, brow, bcol, tid, acc);
  const int w = tid >> 6, lane = tid & 63;
  const int fr = lane & 15, fq = lane >> 4;
  const int r0 = brow + (w >> 1) * 64 + fq * 4;
  const int c0 = bcol + (w & 1) * 64 + fr;
#pragma unroll
  for (int m = 0; m < 4; ++m)
#pragma unroll
    for (int n = 0; n < 4; ++n)
#pragma unroll
      for (int r = 0; r < 4; ++r)
        Out[(size_t)(r0 + m * 16 + r) * HID + c0 + n * 16] = acc[m][n][r];
}

// ---------------- RoPE + per-head relayout ----------------
__global__ __launch_bounds__(256) void rope_kernel(const unsigned short* __restrict__ In,
                                                   const float* __restrict__ cosT,
                                                   const float* __restrict__ sinT,
                                                   unsigned short* __restrict__ Out,
                                                   int nh, float scale) {
  int idx = blockIdx.x * 256 + threadIdx.x;
  int j = idx & 63;
  int s = (idx >> 6) & (S_LEN - 1);
  int h = idx >> 17;
  unsigned int pr = *(const unsigned int*)(In + (size_t)s * (nh * HD) + h * HD + 2 * j);
  float q1 = bf2f((unsigned short)(pr & 0xffffu));
  float q2 = bf2f((unsigned short)(pr >> 16));
  float c = cosT[s * 64 + j], sn = sinT[s * 64 + j];
  unsigned short* op = Out + ((size_t)h * S_LEN + s) * HD + j;
  op[0]  = f2bf(scale * (q1 * c - q2 * sn));
  op[64] = f2bf(scale * (q2 * c + q1 * sn));
}

// ---------------- Flash attention: LDS-staged K/V, double-buffered 2-phase ----------------
__global__ __launch_bounds__(256) void attn_fwd(const unsigned short* __restrict__ Qr,
                                                const unsigned short* __restrict__ Kr,
                                                const unsigned short* __restrict__ Vt,
                                                unsigned short* __restrict__ Ao) {
  __shared__ unsigned short Kl[2][64 * 128];  // [kv][128], swizzled (cb ^ (row&7)<<4)
  __shared__ unsigned short Vl[2][64 * 128];  // [d][kv] 128 rows x 64, swizzled
  __shared__ unsigned short Pl[4][16 * 72];   // per-wave P [16 q][64 kv], stride 72
  const int id = blockIdx.x;
  const int swz = (id & 7) * 128 + (id >> 3);   // XCD c <-> kv-head c
  const int h  = swz >> 5;
  const int qt = 31 - (swz & 31);               // heavy blocks first
  const int hk = h >> 2;
  const int qb = qt * 64;
  const int tid = threadIdx.x, w = tid >> 6, lane = tid & 63;
  const int fr = lane & 15, fq = lane >> 4;

  short8v aq[4];
  {
    const unsigned short* qp = Qr + ((size_t)(h * S_LEN + qb + w * 16 + fr)) * HD + fq * 8;
#pragma unroll
    for (int ks = 0; ks < 4; ++ks) aq[ks] = *(const short8v*)(qp + ks * 32);
  }

  const int kcb = ((tid & 15) * 16) ^ (((tid >> 4) & 7) << 4);
  const unsigned short* pK0 = Kr + ((size_t)hk * S_LEN + (tid >> 4)) * HD + (kcb >> 1);
  const int vcb = ((tid & 7) * 16) ^ (((tid >> 3) & 7) << 4);
  const unsigned short* pV0 = Vt + ((size_t)hk * HD + (tid >> 3)) * S_LEN + (vcb >> 1);

  float m_r[4] = {-1e30f, -1e30f, -1e30f, -1e30f};
  float l_r[4] = {0.f, 0.f, 0.f, 0.f};
  floatx4 o[8] = {};

#define STAGE(buf, t)                                                          \
  do {                                                                         \
    const unsigned short* pk_ = pK0 + (size_t)(t) * 64 * HD;                   \
    const unsigned short* pv_ = pV0 + (t) * 64;                                \
    _Pragma("unroll")                                                          \
    for (int j = 0; j < 4; ++j)                                                \
      gld_lds16(pk_ + (size_t)j * 16 * HD, &Kl[buf][w * 512 + j * 2048]);      \
    _Pragma("unroll")                                                          \
    for (int j = 0; j < 4; ++j)                                                \
      gld_lds16(pv_ + (size_t)j * 32 * S_LEN, &Vl[buf][w * 512 + j * 2048]);   \
  } while (0)

  STAGE(0, 0);
  asm volatile("s_waitcnt vmcnt(0)" ::: "memory");
  __syncthreads();

  int cur = 0;
  for (int t = 0; t <= qt; ++t) {
    const int kv0 = t * 64;
    if (t < qt) STAGE(cur ^ 1, t + 1);

    floatx4 s4[4] = {};
    const unsigned short* Kc = &Kl[cur][0];
    const unsigned short* Vc = &Vl[cur][0];
#pragma unroll
    for (int ks = 0; ks < 4; ++ks) {
#pragma unroll
      for (int n = 0; n < 4; ++n) {
        int row = n * 16 + fr;
        int cb = (ks * 64 + fq * 16) ^ ((row & 7) << 4);
        short8v bk = *(const short8v*)&Kc[row * 128 + (cb >> 1)];
        s4[n] = __builtin_amdgcn_mfma_f32_16x16x32_bf16(aq[ks], bk, s4[n], 0, 0, 0);
      }
    }

    if (t == qt) {
#pragma unroll
      for (int n = 0; n < 4; ++n) {
        int col = kv0 + n * 16 + fr;
#pragma unroll
        for (int r = 0; r < 4; ++r) {
          int rowq = qb + w * 16 + fq * 4 + r;
          if (col > rowq) s4[n][r] = -1e30f;
        }
      }
    }

    float vmax[4];
#pragma unroll
    for (int r = 0; r < 4; ++r)
      vmax[r] = fmaxf(fmaxf(s4[0][r], s4[1][r]), fmaxf(s4[2][r], s4[3][r]));
#pragma unroll
    for (int off = 8; off; off >>= 1)
#pragma unroll
      for (int r = 0; r < 4; ++r)
        vmax[r] = fmaxf(vmax[r], __shfl_xor(vmax[r], off));

    float alpha[4], psum[4] = {0.f, 0.f, 0.f, 0.f};
#pragma unroll
    for (int r = 0; r < 4; ++r) {
      float mn = fmaxf(m_r[r], vmax[r]);
      alpha[r] = __expf(m_r[r] - mn);
      m_r[r] = mn;
    }
#pragma unroll
    for (int n = 0; n < 4; ++n)
#pragma unroll
      for (int r = 0; r < 4; ++r) {
        float p = __expf(s4[n][r] - m_r[r]);
        psum[r] += p;
        Pl[w][(fq * 4 + r) * 72 + n * 16 + fr] = f2bf(p);
      }
#pragma unroll
    for (int r = 0; r < 4; ++r) l_r[r] = l_r[r] * alpha[r] + psum[r];
#pragma unroll
    for (int nf = 0; nf < 8; ++nf)
#pragma unroll
      for (int r = 0; r < 4; ++r) o[nf][r] *= alpha[r];

    short8v pa[2];
#pragma unroll
    for (int ks = 0; ks < 2; ++ks)
      pa[ks] = *(const short8v*)&Pl[w][fr * 72 + ks * 32 + fq * 8];
#pragma unroll
    for (int nf = 0; nf < 8; ++nf) {
#pragma unroll
      for (int ks = 0; ks < 2; ++ks) {
        int row = nf * 16 + fr;
        int cb = (ks * 64 + fq * 16) ^ ((row & 7) << 4);
        short8v bv = *(const short8v*)&Vc[row * 64 + (cb >> 1)];
        o[nf] = __builtin_amdgcn_mfma_f32_16x16x32_bf16(pa[ks], bv, o[nf], 0, 0, 0);
      }
    }

    if (t < qt) {
      asm volatile("s_waitcnt vmcnt(0)" ::: "memory");
      __syncthreads();
      cur ^= 1;
    }
  }
#undef STAGE

  float lsum[4];
#pragma unroll
  for (int r = 0; r < 4; ++r) lsum[r] = l_r[r];
#pragma unroll
  for (int off = 8; off; off >>= 1)
#pragma unroll
    for (int r = 0; r < 4; ++r) lsum[r] += __shfl_xor(lsum[r], off);
  float rinv[4];
#pragma unroll
  for (int r = 0; r < 4; ++r) rinv[r] = 1.0f / lsum[r];

  unsigned short* aop = Ao + (size_t)(qb + w * 16 + fq * 4) * HID + h * HD + fr;
#pragma unroll
  for (int nf = 0; nf < 8; ++nf)
#pragma unroll
    for (int r = 0; r < 4; ++r)
      aop[(size_t)r * HID + nf * 16] = f2bf(o[nf][r] * rinv[r]);
}

// ---------------- launch ----------------
extern "C" void kernel_launch(void* const* d_in, const int* in_sizes, int n_in,
                              void* d_out, int out_size, void* d_ws, size_t ws_size,
                              hipStream_t stream) {
  (void)in_sizes; (void)n_in; (void)out_size; (void)ws_size;
  const float* X    = (const float*)d_in[0];
  const float* cosT = (const float*)d_in[3];
  const float* sinT = (const float*)d_in[4];
  const float* Wq   = (const float*)d_in[5];
  const float* Wk   = (const float*)d_in[6];
  const float* Wv   = (const float*)d_in[7];
  const float* Wo   = (const float*)d_in[8];

  char* ws = (char*)d_ws;
  size_t off = 0;
  auto alloc = [&](size_t bytes) { char* p = ws + off; off += (bytes + 255) & ~(size_t)255; return p; };
  unsigned short* Xb  = (unsigned short*)alloc((size_t)S_LEN * HID * 2);
  unsigned short* Wqb = (unsigned short*)alloc((size_t)HID * HID * 2);
  unsigned short* Wkb = (unsigned short*)alloc((size_t)1024 * HID * 2);
  unsigned short* Wvb = (unsigned short*)alloc((size_t)1024 * HID * 2);
  unsigned short* Wob = (unsigned short*)alloc((size_t)HID * HID * 2);
  unsigned short* Qg  = (unsigned short*)alloc((size_t)S_LEN * HID * 2);
  unsigned short* Kg  = (unsigned short*)alloc((size_t)S_LEN * 1024 * 2);
  unsigned short* Vt  = (unsigned short*)alloc((size_t)1024 * S_LEN * 2);
  unsigned short* Qr = Wqb;                              // aliases, stream-ordered lifetimes
  unsigned short* Kr = Wqb + (size_t)NH * S_LEN * HD;
  unsigned short* Ao = Xb;

  cvt_all<<<2048, 256, 0, stream>>>(X, Wq, Wk, Wv, Wo, Xb, Wqb, Wkb, Wvb, Wob);
  gemm_qkv<<<dim3(48, 8), 512, 0, stream>>>(Xb, Wqb, Wkb, Wvb, Qg, Kg, Vt);
  rope_kernel<<<(NH * S_LEN * 64) / 256, 256, 0, stream>>>(Qg, cosT, sinT, Qr, NH, 0.08838834764831845f);
  rope_kernel<<<(NKV * S_LEN * 64) / 256, 256, 0, stream>>>(Kg, cosT, sinT, Kr, NKV, 1.0f);
  attn_fwd<<<1024, 256, 0, stream>>>(Qr, Kr, Vt, Ao);
  gemm_o<<<dim3(32, 8), 512, 0, stream>>>(Ao, Wob, (float*)d_out);
}